// Round 10
// baseline (102.678 us; speedup 1.0000x reference)
//
#include <hip/hip_runtime.h>

#define A_TOTAL 34000

// Levels (H=W=640): L0 G=160 s=4  a=16  base=0      (25600 anchors, 100 16x16 tiles)
//                   L1 G=80  s=8  a=32  base=25600  ( 6400 anchors,  25 16x16 tiles)
//                   L2 G=40  s=16 a=64  base=32000  ( 1600 anchors,   7 chunks of 256)
//                   L3 G=20  s=32 a=128 base=33600  (  400 anchors,   2 chunks of 256)
// grid = (134, 4): each block handles its anchor tile for FOUR batches.
// Wave w stages batch 4*gy+w (loads, cull ballot, ordered compaction into its
// own LDS list) -> ONE barrier -> every thread runs 4 counted survivor walks
// (v9's bit-exact inner loop) + 4 stores. Amortizes the per-wave fixed cost
// (the ~16us invariant identified from rounds 4-9) 4x.

__global__ __launch_bounds__(256) void multi_anchor_encode_v10(
    const float* __restrict__ boxes,   // [B, 128, 4] yxyx f32
    float* __restrict__ out)           // [B, A_TOTAL, 5] f32
{
    __shared__ float4 cbox[4][128];    // per-batch compacted survivors (ascending)
    __shared__ float  carea[4][128];
    __shared__ int    scnt[4];

    const int t    = threadIdx.x;
    const int bid  = blockIdx.x;
    const int b0   = blockIdx.y << 2;  // batches b0..b0+3
    const int w    = t >> 6;           // wave id 0..3 = staged batch offset
    const int lane = t & 63;

    // ---- Anchor decode + block-uniform conservative tile bounds ----
    int   ia = 0, ja = 0, a_flat = 0;
    float s = 4.f, asize = 16.f;
    bool  valid = true;
    float ty0, ty1, tx0, tx1;

    if (bid < 100) {                       // L0: 16x16 tile
        int ty = bid / 10, tx = bid - ty * 10;
        int i0 = ty * 16, j0 = tx * 16;
        ia = i0 + (t >> 4); ja = j0 + (t & 15);
        s = 4.f; asize = 16.f;
        a_flat = ia * 160 + ja;
        ty0 = (float)(i0 * 4 - 8);  ty1 = (float)((i0 + 15) * 4 + 8);
        tx0 = (float)(j0 * 4 - 8);  tx1 = (float)((j0 + 15) * 4 + 8);
    } else if (bid < 125) {                // L1: 16x16 tile
        int q = bid - 100; int ty = q / 5, tx = q - ty * 5;
        int i0 = ty * 16, j0 = tx * 16;
        ia = i0 + (t >> 4); ja = j0 + (t & 15);
        s = 8.f; asize = 32.f;
        a_flat = 25600 + ia * 80 + ja;
        ty0 = (float)(i0 * 8 - 16); ty1 = (float)((i0 + 15) * 8 + 16);
        tx0 = (float)(j0 * 8 - 16); tx1 = (float)((j0 + 15) * 8 + 16);
    } else if (bid < 132) {                // L2: flat chunks of 256 (y-band cull)
        int c = bid - 125; int k = c * 256 + t;
        valid = (k < 1600); int kk = valid ? k : 0;
        ia = kk / 40; ja = kk - ia * 40;
        s = 16.f; asize = 64.f;
        a_flat = 32000 + kk;
        int klo = c * 256, khi = (klo + 255 < 1599) ? klo + 255 : 1599;
        int ilo = klo / 40, ihi = khi / 40;
        ty0 = (float)(ilo * 16 - 32); ty1 = (float)(ihi * 16 + 32);
        tx0 = -1e30f; tx1 = 1e30f;
    } else {                               // L3: flat chunks of 256 (y-band cull)
        int c = bid - 132; int k = c * 256 + t;
        valid = (k < 400); int kk = valid ? k : 0;
        ia = kk / 20; ja = kk - ia * 20;
        s = 32.f; asize = 128.f;
        a_flat = 33600 + kk;
        int klo = c * 256, khi = (klo + 255 < 399) ? klo + 255 : 399;
        int ilo = klo / 20, ihi = khi / 20;
        ty0 = (float)(ilo * 32 - 64); ty1 = (float)(ihi * 32 + 64);
        tx0 = -1e30f; tx1 = 1e30f;
    }

    // ---- Wave w stages batch b0+w: load, cull, ordered compaction ----
    // Bounds are block-uniform, so wave w's ballot over its batch's boxes is
    // exactly that batch's survivor mask. Conservative >=/<= tests: a culled
    // box provably has inter==0 with every anchor of this tile.
    {
        const float4* bbk = reinterpret_cast<const float4*>(boxes + (size_t)(b0 + w) * 128 * 4);
        float4 vA = bbk[lane];             // x=ymin y=xmin z=ymax w=xmax
        float4 vB = bbk[lane + 64];
        bool kA = (vA.z >= ty0) && (vA.x <= ty1) && (vA.w >= tx0) && (vA.y <= tx1);
        bool kB = (vB.z >= ty0) && (vB.x <= ty1) && (vB.w >= tx0) && (vB.y <= tx1);
        unsigned long long mA = __ballot(kA);
        unsigned long long mB = __ballot(kB);
        unsigned long long below = (1ull << lane) - 1ull;
        if (kA) {
            int p = __popcll(mA & below);
            cbox[w][p]  = vA;
            carea[w][p] = __fmul_rn(__fsub_rn(vA.z, vA.x), __fsub_rn(vA.w, vA.y));
        }
        if (kB) {
            int p = __popcll(mA) + __popcll(mB & below);
            cbox[w][p]  = vB;
            carea[w][p] = __fmul_rn(__fsub_rn(vB.z, vB.x), __fsub_rn(vB.w, vB.y));
        }
        if (lane == 0) scnt[w] = __popcll(mA) + __popcll(mB);
    }
    __syncthreads();                       // the ONLY barrier

    const float half   = asize * 0.5f;     // exact (power of two)
    const float area_a = asize * asize;    // exact
    const float cy = (float)ia * s, cx = (float)ja * s;  // exact ints in f32
    const float ay0 = cy - half, ax0 = cx - half;
    const float ay1 = cy + half, ax1 = cx + half;
    const float inv = 1.0f / asize;        // exact power of two

    // ---- Four walks (one per batch), v9's proven bit-exact inner loop ----
    #pragma unroll 1
    for (int k = 0; k < 4; ++k) {
        const int cnt = scnt[k];           // LDS broadcast (wave-uniform)
        float  best = 0.0f; int bl = 0;
        double bn_d = 0.0,  bd_d = 1.0;
        #pragma unroll 4
        for (int m = 0; m < cnt; ++m) {
            float4 v  = cbox[k][m];        // wave-uniform LDS broadcast
            float  sa = carea[k][m];
            float ymin = fmaxf(ay0, v.x);
            float xmin = fmaxf(ax0, v.y);
            float ymax = fminf(ay1, v.z);
            float xmax = fminf(ax1, v.w);
            float ih   = fmaxf(__fsub_rn(ymax, ymin), 0.0f);
            float iw   = fmaxf(__fsub_rn(xmax, xmin), 0.0f);
            float inter = __fmul_rn(ih, iw);
            float denom = __fsub_rn(__fadd_rn(area_a, sa), inter);
            // f64 cross-multiply filter: EXACT (24+24 < 53 bits) ordering of
            // real quotients; rounding monotonicity => no false negatives vs
            // numpy's rounded compare; rounded fdiv confirm keeps the update
            // decision bit-identical to np.argmax's first-max semantics.
            double id = (double)inter, dd = (double)denom;
            if (id * bd_d > bn_d * dd) {
                float iou = __fdiv_rn(inter, denom);   // IEEE == numpy f32
                if (iou > best) { best = iou; bl = m; bn_d = id; bd_d = dd; }
            }
        }

        if (valid) {
            // Matched box: compacted entry, or original box 0 if all IoU == 0
            // (np.argmax of an all-zero row -> index 0; box 0 may be culled,
            // so re-read it from global — L1/L2-hot, exec-safe per-lane load).
            float4 mbx;
            if (best > 0.0f) mbx = cbox[k][bl];
            else mbx = reinterpret_cast<const float4*>(boxes + (size_t)(b0 + k) * 128 * 4)[0];
            float mcy = __fmul_rn(__fadd_rn(mbx.x, mbx.z), 0.5f);
            float mcx = __fmul_rn(__fadd_rn(mbx.y, mbx.w), 0.5f);
            float mh  = __fsub_rn(mbx.z, mbx.x);
            float mw  = __fsub_rn(mbx.w, mbx.y);
            size_t o = ((size_t)(b0 + k) * A_TOTAL + a_flat) * 5;
            out[o + 0] = best;
            out[o + 1] = __fmul_rn(__fsub_rn(mcy, cy), inv);
            out[o + 2] = __fmul_rn(__fsub_rn(mcx, cx), inv);
            out[o + 3] = __fmul_rn(__fsub_rn(mh, asize), inv);
            out[o + 4] = __fmul_rn(__fsub_rn(mw, asize), inv);
        }
    }
}

extern "C" void kernel_launch(void* const* d_in, const int* in_sizes, int n_in,
                              void* d_out, int out_size, void* d_ws, size_t ws_size,
                              hipStream_t stream) {
    const float* boxes = (const float*)d_in[0];
    float* out = (float*)d_out;
    dim3 grid(134, 4 /*B/4*/);
    multi_anchor_encode_v10<<<grid, 256, 0, stream>>>(boxes, out);
}

// Round 11
// 70.768 us; speedup vs baseline: 1.4509x; 1.4509x over previous
//
#include <hip/hip_runtime.h>

#define A_TOTAL 34000

// Fine-grained decomposition: 267 tiles x 16 batches = 4272 blocks of 128 thr
// (2 waves). v10 counters (Occ 4.6%) showed the masked kernels are
// tail/granularity-bound => many short blocks beat few long ones.
//   L0: 16x8 anchor tiles (10 j x 20 i) = 200 blocks, s=4,  a=16,  base 0
//   L1: 16x8 tiles        ( 5 j x 10 i) =  50 blocks, s=8,  a=32,  base 25600
//   L2: flat 128-chunks   (13, y-band)              , s=16, a=64,  base 32000
//   L3: flat 128-chunks   ( 4, y-band)              , s=32, a=128, base 33600

__global__ __launch_bounds__(128) void multi_anchor_encode_v11(
    const float* __restrict__ boxes,   // [B, 128, 4] yxyx f32
    float* __restrict__ out)           // [B, A_TOTAL, 5] f32
{
    __shared__ float4 cbox[128];   // compacted survivors, ascending box order
    __shared__ float  csum[128];   // area_a + area_box (pre-added, rn)
    __shared__ int    scnt;

    const int b    = blockIdx.y;
    const int t    = threadIdx.x;      // 0..127
    const int bid  = blockIdx.x;
    const int w    = t >> 6;           // wave 0 | 1
    const int lane = t & 63;

    // ---- Anchor decode + block-uniform conservative tile bounds ----
    int   ia = 0, ja = 0, a_flat = 0;
    float s = 4.f, asize = 16.f;
    bool  valid = true;
    float ty0, ty1, tx0, tx1;

    if (bid < 200) {                       // L0: 16 cols x 8 rows
        int ty = bid / 10, tx = bid - ty * 10;       // ty 0..19, tx 0..9
        int i0 = ty * 8, j0 = tx * 16;
        ia = i0 + (t >> 4); ja = j0 + (t & 15);      // rows 0..7, cols 0..15
        s = 4.f; asize = 16.f;
        a_flat = ia * 160 + ja;
        ty0 = (float)(i0 * 4 - 8);  ty1 = (float)((i0 + 7) * 4 + 8);
        tx0 = (float)(j0 * 4 - 8);  tx1 = (float)((j0 + 15) * 4 + 8);
    } else if (bid < 250) {                // L1: 16 cols x 8 rows
        int q = bid - 200; int ty = q / 5, tx = q - ty * 5;  // ty 0..9, tx 0..4
        int i0 = ty * 8, j0 = tx * 16;
        ia = i0 + (t >> 4); ja = j0 + (t & 15);
        s = 8.f; asize = 32.f;
        a_flat = 25600 + ia * 80 + ja;
        ty0 = (float)(i0 * 8 - 16); ty1 = (float)((i0 + 7) * 8 + 16);
        tx0 = (float)(j0 * 8 - 16); tx1 = (float)((j0 + 15) * 8 + 16);
    } else if (bid < 263) {                // L2: flat chunks of 128 (y-band)
        int c = bid - 250; int k = c * 128 + t;
        valid = (k < 1600); int kk = valid ? k : 0;
        ia = kk / 40; ja = kk - ia * 40;
        s = 16.f; asize = 64.f;
        a_flat = 32000 + kk;
        int klo = c * 128, khi = (klo + 127 < 1599) ? klo + 127 : 1599;
        int ilo = klo / 40, ihi = khi / 40;
        ty0 = (float)(ilo * 16 - 32); ty1 = (float)(ihi * 16 + 32);
        tx0 = -1e30f; tx1 = 1e30f;
    } else {                               // L3: flat chunks of 128 (y-band)
        int c = bid - 263; int k = c * 128 + t;
        valid = (k < 400); int kk = valid ? k : 0;
        ia = kk / 20; ja = kk - ia * 20;
        s = 32.f; asize = 128.f;
        a_flat = 33600 + kk;
        int klo = c * 128, khi = (klo + 127 < 399) ? klo + 127 : 399;
        int ilo = klo / 20, ihi = khi / 20;
        ty0 = (float)(ilo * 32 - 64); ty1 = (float)(ihi * 32 + 64);
        tx0 = -1e30f; tx1 = 1e30f;
    }

    const float area_a = asize * asize;    // exact (block-uniform)

    // ---- Staging: BOTH waves load all 128 boxes and compute IDENTICAL
    // ballots (bounds are block-uniform). Wave 0 compacts the low half,
    // wave 1 the high half (its prefix uses its own popcll(mA)). scnt is
    // published before the single barrier. Conservative >=/<= tests: a
    // culled box provably has inter==0 with every anchor of this tile.
    const float4* bb = reinterpret_cast<const float4*>(boxes + (size_t)b * 128 * 4);
    {
        float4 vA = bb[lane];              // x=ymin y=xmin z=ymax w=xmax
        float4 vB = bb[lane + 64];
        bool kA = (vA.z >= ty0) && (vA.x <= ty1) && (vA.w >= tx0) && (vA.y <= tx1);
        bool kB = (vB.z >= ty0) && (vB.x <= ty1) && (vB.w >= tx0) && (vB.y <= tx1);
        unsigned long long mA = __ballot(kA);
        unsigned long long mB = __ballot(kB);
        unsigned long long below = (1ull << lane) - 1ull;
        if (w == 0) {
            if (kA) {
                int p = __popcll(mA & below);
                cbox[p] = vA;
                csum[p] = __fadd_rn(area_a,
                          __fmul_rn(__fsub_rn(vA.z, vA.x), __fsub_rn(vA.w, vA.y)));
            }
        } else {
            if (kB) {
                int p = __popcll(mA) + __popcll(mB & below);
                cbox[p] = vB;
                csum[p] = __fadd_rn(area_a,
                          __fmul_rn(__fsub_rn(vB.z, vB.x), __fsub_rn(vB.w, vB.y)));
            }
        }
        if (t == 0) scnt = __popcll(mA) + __popcll(mB);
    }
    __syncthreads();                       // the ONLY barrier

    const float half = asize * 0.5f;       // exact (power of two)
    const float cy = (float)ia * s, cx = (float)ja * s;  // exact ints in f32
    const float ay0 = cy - half, ax0 = cx - half;
    const float ay1 = cy + half, ax1 = cx + half;
    const float inv = 1.0f / asize;        // exact power of two

    const int cnt = scnt;                  // wave-uniform LDS broadcast

    // ---- Counted survivor walk (v9's proven bit-exact accept path) ----
    float  best = 0.0f; int bl = 0;
    double bn_d = 0.0,  bd_d = 1.0;
    #pragma unroll 4
    for (int m = 0; m < cnt; ++m) {
        float4 v  = cbox[m];               // wave-uniform LDS broadcast
        float  su = csum[m];               // area_a + area_b (pre-added, rn)
        float ymin = fmaxf(ay0, v.x);
        float xmin = fmaxf(ax0, v.y);
        float ymax = fminf(ay1, v.z);
        float xmax = fminf(ax1, v.w);
        float ih   = fmaxf(__fsub_rn(ymax, ymin), 0.0f);
        float iw   = fmaxf(__fsub_rn(xmax, xmin), 0.0f);
        float inter = __fmul_rn(ih, iw);
        float denom = __fsub_rn(su, inter);   // == (area_a+sa)-inter, rn order
        // Exact f64 cross-multiply filter (24+24<53 bits): real-quotient order
        // + rounding monotonicity => skips provably safe; rounded fdiv confirm
        // keeps the update decision bit-identical to np.argmax first-max.
        double id = (double)inter, dd = (double)denom;
        if (id * bd_d > bn_d * dd) {
            float iou = __fdiv_rn(inter, denom);   // IEEE == numpy f32
            if (iou > best) { best = iou; bl = m; bn_d = id; bd_d = dd; }
        }
    }

    if (!valid) return;

    // Matched box: compacted entry, or original box 0 if all IoU == 0
    // (np.argmax of all-zero row -> 0; box 0 may be culled -> global re-read).
    float4 mbx;
    if (best > 0.0f) mbx = cbox[bl];       // per-lane ds_read, exec-safe
    else             mbx = bb[0];          // L1/L2-hot, exec-safe
    float mcy = __fmul_rn(__fadd_rn(mbx.x, mbx.z), 0.5f);
    float mcx = __fmul_rn(__fadd_rn(mbx.y, mbx.w), 0.5f);
    float mh  = __fsub_rn(mbx.z, mbx.x);
    float mw  = __fsub_rn(mbx.w, mbx.y);

    size_t o = ((size_t)b * A_TOTAL + a_flat) * 5;
    out[o + 0] = best;
    out[o + 1] = __fmul_rn(__fsub_rn(mcy, cy), inv);
    out[o + 2] = __fmul_rn(__fsub_rn(mcx, cx), inv);
    out[o + 3] = __fmul_rn(__fsub_rn(mh, asize), inv);
    out[o + 4] = __fmul_rn(__fsub_rn(mw, asize), inv);
}

extern "C" void kernel_launch(void* const* d_in, const int* in_sizes, int n_in,
                              void* d_out, int out_size, void* d_ws, size_t ws_size,
                              hipStream_t stream) {
    const float* boxes = (const float*)d_in[0];
    float* out = (float*)d_out;
    dim3 grid(267, 16 /*B*/);
    multi_anchor_encode_v11<<<grid, 128, 0, stream>>>(boxes, out);
}